// Round 1
// baseline (598.588 us; speedup 1.0000x reference)
//
#include <hip/hip_runtime.h>
#include <stdint.h>
#include <math.h>

// ---------------------------------------------------------------------------
// HardNegativeMiner: replicate JAX threefry PRNG bit-exactly, fused GEMV/GEMM
// argmax (Gumbel-max categorical), then mix rows.
//
// PRNG variant: JAX >= 0.5 defaults threefry_partitionable=True.
//   random_bits 32: out[p] = x0 ^ x1 of threefry(key, (0, p))
//   split:          keys[i] = threefry(key, (0, i))  (both words)
// Legacy scheme kept behind PRNG_PARTITIONABLE=0 for a one-line flip if the
// bench comes back with absmax ~O(1) (index-mismatch signature).
// ---------------------------------------------------------------------------
#define PRNG_PARTITIONABLE 1

#define BN 16384   // batch
#define DK 256     // dim
#define NH 3276    // int(16384*0.2)
#define JT 64      // j-tile
#define CT 64      // c-tile
#define NJT 52     // ceil(NH/JT)
#define NCT 256    // BN/CT
#define HALF_G 26836992u  // (NH*BN)/2, for legacy gumbel pairing
#define HALF_S 1638u      // NH/2, for legacy 1-D bit pairing

__host__ __device__ __forceinline__ void tf2x32(uint32_t k0, uint32_t k1,
                                                uint32_t c0, uint32_t c1,
                                                uint32_t& o0, uint32_t& o1) {
  uint32_t ks2 = 0x1BD11BDAu ^ k0 ^ k1;
  uint32_t x0 = c0 + k0, x1 = c1 + k1;
#define RR(d) { x0 += x1; x1 = (x1 << d) | (x1 >> (32 - d)); x1 ^= x0; }
  RR(13) RR(15) RR(26) RR(6)   x0 += k1;  x1 += ks2 + 1u;
  RR(17) RR(29) RR(16) RR(24)  x0 += ks2; x1 += k0  + 2u;
  RR(13) RR(15) RR(26) RR(6)   x0 += k0;  x1 += k1  + 3u;
  RR(17) RR(29) RR(16) RR(24)  x0 += k1;  x1 += ks2 + 4u;
  RR(13) RR(15) RR(26) RR(6)   x0 += ks2; x1 += k0  + 5u;
#undef RR
  o0 = x0; o1 = x1;
}

// 32-bit random word at flat position p for a given key (matches jax
// random_bits(key, 32, shape) at flat index p).
__device__ __forceinline__ uint32_t rand32_at(uint32_t k0, uint32_t k1,
                                              uint32_t p, uint32_t half) {
#if PRNG_PARTITIONABLE
  (void)half;
  uint32_t x0, x1; tf2x32(k0, k1, 0u, p, x0, x1);
  return x0 ^ x1;
#else
  uint32_t x0, x1;
  if (p < half) { tf2x32(k0, k1, p, p + half, x0, x1); return x0; }
  else          { tf2x32(k0, k1, p - half, p, x0, x1); return x1; }
#endif
}

// uniform(key,...)[p] bit pattern -> float in [0,1)
__device__ __forceinline__ float unif01_from_bits(uint32_t bits) {
  return __uint_as_float((bits >> 9) | 0x3f800000u) - 1.0f;
}

__device__ __forceinline__ float gumbel_at(uint32_t k0, uint32_t k1, uint32_t p) {
  uint32_t bits = rand32_at(k0, k1, p, HALF_G);
  float f = unif01_from_bits(bits);
  float u = fmaxf(f, 1.17549435e-38f);  // minval = finfo(f32).tiny
  return -logf(-logf(u));
}

// monotonic float->uint32 map; pack (value, ~col): max => larger val, tie => smaller col
__device__ __forceinline__ unsigned long long packvc(float v, uint32_t c) {
  uint32_t u = __float_as_uint(v);
  u ^= ((int32_t)u < 0) ? 0xFFFFFFFFu : 0x80000000u;
  return ((unsigned long long)u << 32) | (unsigned long long)(~c);
}

// ---------------------------------------------------------------------------
__global__ __launch_bounds__(256) void k_norm(const float* __restrict__ z,
                                              float* __restrict__ inv_norm) {
  int row  = blockIdx.x * 4 + (threadIdx.x >> 6);
  int lane = threadIdx.x & 63;
  float4 v = *(const float4*)&z[row * DK + lane * 4];
  float ss = v.x * v.x + v.y * v.y + v.z * v.z + v.w * v.w;
#pragma unroll
  for (int off = 32; off; off >>= 1) ss += __shfl_xor(ss, off, 64);
  if (lane == 0) inv_norm[row] = 1.0f / fmaxf(sqrtf(ss), 1e-12f);
}

__global__ __launch_bounds__(256) void k_setup(int* __restrict__ src_idx,
                                               unsigned long long* __restrict__ best,
                                               uint32_t k20, uint32_t k21) {
  int i = blockIdx.x * 256 + threadIdx.x;
  if (i < NH) {
    uint32_t bits = rand32_at(k20, k21, (uint32_t)i, HALF_S);
    // randint(0, 16384): span=2^14 -> multiplier term vanishes -> lower & 16383
    src_idx[i] = (int)(bits & (uint32_t)(BN - 1));
    best[i] = 0ull;
  }
}

// fused GEMM (A = z[src rows], B = z, K = 256) + gumbel + argmax
__global__ __launch_bounds__(256) void k_main(const float* __restrict__ z,
                                              const float* __restrict__ inv_norm,
                                              const int* __restrict__ src_idx,
                                              unsigned long long* __restrict__ best,
                                              uint32_t kt0, uint32_t kt1) {
  __shared__ float As[JT * 64];  // [j][k-chunk], column-quad XOR-swizzled
  __shared__ float Bs[CT * 64];

  const int ct = blockIdx.x, jt = blockIdx.y;
  const int c_base = ct * CT, j_base = jt * JT;
  const int t  = threadIdx.x;
  const int cq = t & 15;   // c-quad this thread accumulates (4 cols)
  const int jq = t >> 4;   // j-quad this thread accumulates (4 rows)

  // staging rows owned by this thread (same for A and B maps)
  int arow[4];
#pragma unroll
  for (int r = 0; r < 4; ++r) {
    int gj = j_base + (t >> 4) + 16 * r;
    arow[r] = src_idx[min(gj, NH - 1)];
  }

  float acc[4][4];
#pragma unroll
  for (int jj = 0; jj < 4; ++jj)
#pragma unroll
    for (int cc = 0; cc < 4; ++cc) acc[jj][cc] = 0.0f;

  for (int kc = 0; kc < 4; ++kc) {
    const int k0 = kc * 64;
    // stage A: 64 rows x 64 k. thread: rows (t>>4)+16r, k-quad t&15
#pragma unroll
    for (int r = 0; r < 4; ++r) {
      int j = (t >> 4) + 16 * r;
      float4 v = *(const float4*)&z[arow[r] * DK + k0 + (t & 15) * 4];
      int col = (t & 15) ^ ((j >> 2) & 15);
      *(float4*)&As[j * 64 + col * 4] = v;
    }
    // stage B
#pragma unroll
    for (int r = 0; r < 4; ++r) {
      int c = (t >> 4) + 16 * r;
      float4 v = *(const float4*)&z[(c_base + c) * DK + k0 + (t & 15) * 4];
      int col = (t & 15) ^ ((c >> 2) & 15);
      *(float4*)&Bs[c * 64 + col * 4] = v;
    }
    __syncthreads();

#pragma unroll
    for (int q = 0; q < 16; ++q) {
      float4 av[4], bv[4];
#pragma unroll
      for (int jj = 0; jj < 4; ++jj)
        av[jj] = *(const float4*)&As[(jq * 4 + jj) * 64 + ((q ^ jq) & 15) * 4];
#pragma unroll
      for (int cc = 0; cc < 4; ++cc)
        bv[cc] = *(const float4*)&Bs[(cq * 4 + cc) * 64 + ((q ^ cq) & 15) * 4];
#pragma unroll
      for (int jj = 0; jj < 4; ++jj)
#pragma unroll
        for (int cc = 0; cc < 4; ++cc) {
          acc[jj][cc] += av[jj].x * bv[cc].x;
          acc[jj][cc] += av[jj].y * bv[cc].y;
          acc[jj][cc] += av[jj].z * bv[cc].z;
          acc[jj][cc] += av[jj].w * bv[cc].w;
        }
    }
    __syncthreads();
  }

  // epilogue: logits + gumbel, per-j argmax over this block's 64 cols
  const int cbase4 = c_base + cq * 4;
  float invc[4];
#pragma unroll
  for (int cc = 0; cc < 4; ++cc) invc[cc] = inv_norm[cbase4 + cc];

#pragma unroll
  for (int jj = 0; jj < 4; ++jj) {
    int gj = j_base + jq * 4 + jj;
    bool valid = (gj < NH);
    int s = src_idx[valid ? gj : (NH - 1)];
    float invs = inv_norm[s];
    float bv = -INFINITY; uint32_t bc = 0;
#pragma unroll
    for (int cc = 0; cc < 4; ++cc) {
      int c = cbase4 + cc;
      float sim = acc[jj][cc] * invs * invc[cc];
      float logit = sim / 0.1f;            // match ref's division by TEMPERATURE
      if (c == s) logit = -INFINITY;       // diagonal mask
      float g = gumbel_at(kt0, kt1, (uint32_t)gj * (uint32_t)BN + (uint32_t)c);
      float tot = logit + g;
      if (tot > bv) { bv = tot; bc = (uint32_t)c; }  // ascending c: first-max kept
    }
    unsigned long long key = packvc(bv, bc);
#pragma unroll
    for (int off = 1; off < 16; off <<= 1) {
      unsigned long long o = __shfl_xor(key, off, 64);
      if (o > key) key = o;
    }
    if (valid && cq == 0) atomicMax(&best[gj], key);
  }
}

__global__ __launch_bounds__(64) void k_out(const float* __restrict__ z,
                                            const int* __restrict__ src_idx,
                                            const unsigned long long* __restrict__ best,
                                            float* __restrict__ out,
                                            uint32_t ka0, uint32_t ka1) {
  int j = blockIdx.x;
  int lane = threadIdx.x;
  int s = src_idx[j];
  int tgt = (int)(~((uint32_t)(best[j] & 0xFFFFFFFFull)));
  uint32_t bits = rand32_at(ka0, ka1, (uint32_t)j, HALF_S);
  float alpha = unif01_from_bits(bits) * 0.5f;   // uniform * MIX_ALPHA
  float om = 1.0f - alpha;
  float4 a = *(const float4*)&z[s * DK + lane * 4];
  float4 b = *(const float4*)&z[tgt * DK + lane * 4];
  float4 o;
  o.x = alpha * a.x + om * b.x;
  o.y = alpha * a.y + om * b.y;
  o.z = alpha * a.z + om * b.z;
  o.w = alpha * a.w + om * b.w;
  *(float4*)&out[j * DK + lane * 4] = o;
}

// ---------------------------------------------------------------------------
extern "C" void kernel_launch(void* const* d_in, const int* in_sizes, int n_in,
                              void* d_out, int out_size, void* d_ws, size_t ws_size,
                              hipStream_t stream) {
  const float* z = (const float*)d_in[0];
  float* out = (float*)d_out;
  char* ws = (char*)d_ws;
  float*              inv_norm = (float*)(ws);                 // 65536 B
  int*                src_idx  = (int*)(ws + 65536);           // 13104 B
  unsigned long long* best     = (unsigned long long*)(ws + 78656); // 26208 B

  // host-side threefry key derivation (deterministic, identical every call)
  uint32_t r0 = 0u, r1 = 42u;
  uint32_t ks0, ks1, kt0, kt1, ka0, ka1, k20, k21;
#if PRNG_PARTITIONABLE
  tf2x32(r0, r1, 0u, 0u, ks0, ks1);   // k_src  = split(root,3)[0]
  tf2x32(r0, r1, 0u, 1u, kt0, kt1);   // k_tgt  = split(root,3)[1]
  tf2x32(r0, r1, 0u, 2u, ka0, ka1);   // k_alpha= split(root,3)[2]
  tf2x32(ks0, ks1, 0u, 1u, k20, k21); // k2 = split(k_src,2)[1] (randint lower bits)
#else
  // legacy (non-partitionable): split via iota halves
  uint32_t a0, a1, b0, b1, c0, c1;
  tf2x32(r0, r1, 0u, 3u, a0, a1);     // pairs (0,3),(1,4),(2,5)
  tf2x32(r0, r1, 1u, 4u, b0, b1);
  tf2x32(r0, r1, 2u, 5u, c0, c1);
  ks0 = a0; ks1 = b0;                 // keys reshaped from [x0s..., x1s...]
  kt0 = c0; kt1 = a1;
  ka0 = b1; ka1 = c1;
  uint32_t u0, u1, v0, v1;
  tf2x32(ks0, ks1, 0u, 2u, u0, u1);   // split(k_src,2): pairs (0,2),(1,3)
  tf2x32(ks0, ks1, 1u, 3u, v0, v1);
  k20 = u1; k21 = v1;                 // second key = (x1 of pair0, x1 of pair1)
#endif

  k_norm <<<dim3(BN / 4), dim3(256), 0, stream>>>(z, inv_norm);
  k_setup<<<dim3((NH + 255) / 256), dim3(256), 0, stream>>>(src_idx, best, k20, k21);
  k_main <<<dim3(NCT, NJT), dim3(256), 0, stream>>>(z, inv_norm, src_idx, best, kt0, kt1);
  k_out  <<<dim3(NH), dim3(64), 0, stream>>>(z, src_idx, best, out, ka0, ka1);
}

// Round 2
// 304.786 us; speedup vs baseline: 1.9640x; 1.9640x over previous
//
#include <hip/hip_runtime.h>
#include <stdint.h>
#include <math.h>

// ---------------------------------------------------------------------------
// HardNegativeMiner round 2: split-bf16 3-pass MFMA GEMM (sim = Ah*Bh + Ah*Bl
// + Al*Bh, error ~2^-16 rel) fused with threefry-gumbel argmax epilogue.
// PRNG chain (partitionable threefry) verified bit-exact in round 1.
// ---------------------------------------------------------------------------
#define BN 16384   // batch
#define DK 256     // dim
#define NH 3276    // int(16384*0.2)
#define MPAD 3328  // 26 * 128
#define NJB 26     // j-strips of 128
#define NCB 128    // c-blocks of 128

typedef __attribute__((ext_vector_type(8))) short short8;
typedef __attribute__((ext_vector_type(4))) float f32x4;

__host__ __device__ __forceinline__ void tf2x32(uint32_t k0, uint32_t k1,
                                                uint32_t c0, uint32_t c1,
                                                uint32_t& o0, uint32_t& o1) {
  uint32_t ks2 = 0x1BD11BDAu ^ k0 ^ k1;
  uint32_t x0 = c0 + k0, x1 = c1 + k1;
#define RR(d) { x0 += x1; x1 = (x1 << d) | (x1 >> (32 - d)); x1 ^= x0; }
  RR(13) RR(15) RR(26) RR(6)   x0 += k1;  x1 += ks2 + 1u;
  RR(17) RR(29) RR(16) RR(24)  x0 += ks2; x1 += k0  + 2u;
  RR(13) RR(15) RR(26) RR(6)   x0 += k0;  x1 += k1  + 3u;
  RR(17) RR(29) RR(16) RR(24)  x0 += k1;  x1 += ks2 + 4u;
  RR(13) RR(15) RR(26) RR(6)   x0 += ks2; x1 += k0  + 5u;
#undef RR
  o0 = x0; o1 = x1;
}

__device__ __forceinline__ uint32_t rand32_at(uint32_t k0, uint32_t k1, uint32_t p) {
  uint32_t x0, x1; tf2x32(k0, k1, 0u, p, x0, x1);
  return x0 ^ x1;
}

__device__ __forceinline__ float unif01_from_bits(uint32_t bits) {
  return __uint_as_float((bits >> 9) | 0x3f800000u) - 1.0f;
}

// gumbel at flat counter p: -log(-log(max(u, tiny))), fast v_log_f32 path
__device__ __forceinline__ float gumbel_at(uint32_t k0, uint32_t k1, uint32_t p) {
  uint32_t bits = rand32_at(k0, k1, p);
  float f = unif01_from_bits(bits);
  float u = fmaxf(f, 1.17549435e-38f);          // minval = finfo(f32).tiny
  float t = __log2f(u) * (-0.69314718055994531f);  // -ln(u) > 0
  return __log2f(t) * (-0.69314718055994531f);     // -ln(t)
}

// monotonic float->u32; pack (value, ~col): max => larger val, tie => smaller col
__device__ __forceinline__ unsigned long long packvc(float v, uint32_t c) {
  uint32_t u = __float_as_uint(v);
  u ^= ((int32_t)u < 0) ? 0xFFFFFFFFu : 0x80000000u;
  return ((unsigned long long)u << 32) | (unsigned long long)(~c);
}

// fp32 -> (bf16 hi, bf16 lo) by truncation; hi+lo ~ f with ~2^-16 rel error
__device__ __forceinline__ void split8(float4 a, float4 b, short8& h, short8& l) {
  float f[8] = {a.x, a.y, a.z, a.w, b.x, b.y, b.z, b.w};
#pragma unroll
  for (int i = 0; i < 8; ++i) {
    uint32_t u = __float_as_uint(f[i]);
    h[i] = (short)(u >> 16);
    float r = f[i] - __uint_as_float(u & 0xFFFF0000u);
    l[i] = (short)(__float_as_uint(r) >> 16);
  }
}

// ---------------------------------------------------------------------------
__global__ __launch_bounds__(256) void k_norm(const float* __restrict__ z,
                                              float* __restrict__ inv_norm) {
  int row  = blockIdx.x * 4 + (threadIdx.x >> 6);
  int lane = threadIdx.x & 63;
  float4 v = *(const float4*)&z[row * DK + lane * 4];
  float ss = v.x * v.x + v.y * v.y + v.z * v.z + v.w * v.w;
#pragma unroll
  for (int off = 32; off; off >>= 1) ss += __shfl_xor(ss, off, 64);
  if (lane == 0) inv_norm[row] = 1.0f / fmaxf(sqrtf(ss), 1e-12f);
}

__global__ __launch_bounds__(256) void k_setup(int* __restrict__ src_idx,
                                               unsigned long long* __restrict__ best,
                                               uint32_t k20, uint32_t k21) {
  int i = blockIdx.x * 256 + threadIdx.x;
  if (i < NH) {
    uint32_t bits = rand32_at(k20, k21, (uint32_t)i);
    src_idx[i] = (int)(bits & (uint32_t)(BN - 1));  // randint span 2^14
    best[i] = 0ull;                                  // identity for packvc keys
  }
}

// ---------------------------------------------------------------------------
// 128x128 block tile, 4 waves of 64x64. K=256 in 4 chunks of 64.
// LDS: hi/lo bf16 tiles for A (gathered src rows) and B (z rows), XOR-swizzled
// in 8-elem (16 B) units so ds_read_b128 fragment loads are conflict-free.
__global__ __launch_bounds__(256, 2) void k_main(const float* __restrict__ z,
                                                 const float* __restrict__ inv_norm,
                                                 const int* __restrict__ src_idx,
                                                 unsigned long long* __restrict__ best,
                                                 uint32_t kt0, uint32_t kt1) {
  __shared__ __align__(16) short As_hi[128 * 64];
  __shared__ __align__(16) short As_lo[128 * 64];
  __shared__ __align__(16) short Bs_hi[128 * 64];
  __shared__ __align__(16) short Bs_lo[128 * 64];

  // XCD-aware swizzle: XCD x owns c-blocks [16x, 16x+16) -> 2 MB B-set per L2
  const int flat = blockIdx.x;                 // 3328 = 8 * (16 * 26)
  const int xcd = flat & 7, slot = flat >> 3;  // slot in [0, 416)
  const int c_base = (xcd * 16 + (slot & 15)) * 128;
  const int j_base = (slot >> 4) * 128;

  const int t = threadIdx.x;
  const int lane = t & 63, w = t >> 6;
  const int g = t & 7;        // staging k-group (8 floats)
  const int srow = t >> 3;    // staging row base (0..31), rows srow+32u

  int arow[4];
#pragma unroll
  for (int u = 0; u < 4; ++u)
    arow[u] = src_idx[min(j_base + srow + 32 * u, NH - 1)];

  f32x4 acc[4][4];
#pragma unroll
  for (int mt = 0; mt < 4; ++mt)
#pragma unroll
    for (int nt = 0; nt < 4; ++nt) acc[mt][nt] = (f32x4){0.f, 0.f, 0.f, 0.f};

  for (int kc = 0; kc < 4; ++kc) {
    const int k0 = kc * 64;
    // ---- stage + convert: 128 rows x 64 k for A and B ----
#pragma unroll
    for (int u = 0; u < 4; ++u) {
      int row = srow + 32 * u;
      int off = row * 64 + ((g ^ (row & 7)) * 8);  // swizzled 16 B unit
      const float* pa = z + (size_t)arow[u] * DK + k0 + g * 8;
      float4 a0 = *(const float4*)pa;
      float4 a1 = *(const float4*)(pa + 4);
      short8 h, l;
      split8(a0, a1, h, l);
      *(short8*)&As_hi[off] = h;
      *(short8*)&As_lo[off] = l;
      const float* pb = z + (size_t)(c_base + row) * DK + k0 + g * 8;
      float4 b0 = *(const float4*)pb;
      float4 b1 = *(const float4*)(pb + 4);
      split8(b0, b1, h, l);
      *(short8*)&Bs_hi[off] = h;
      *(short8*)&Bs_lo[off] = l;
    }
    __syncthreads();

    // ---- MFMA: 2 k-steps of 32, 3 passes ----
    const int cl = lane & 15, q = lane >> 4;
    const int mrow0 = (w >> 1) * 64 + cl;
    const int nrow0 = (w & 1) * 64 + cl;
#pragma unroll
    for (int s = 0; s < 2; ++s) {
      short8 ah[4], al[4], bh[4], bl[4];
#pragma unroll
      for (int mt = 0; mt < 4; ++mt) {
        int row = mrow0 + mt * 16;
        int off = row * 64 + (((s * 4 + q) ^ (row & 7)) * 8);
        ah[mt] = *(const short8*)&As_hi[off];
        al[mt] = *(const short8*)&As_lo[off];
      }
#pragma unroll
      for (int nt = 0; nt < 4; ++nt) {
        int row = nrow0 + nt * 16;
        int off = row * 64 + (((s * 4 + q) ^ (row & 7)) * 8);
        bh[nt] = *(const short8*)&Bs_hi[off];
        bl[nt] = *(const short8*)&Bs_lo[off];
      }
#pragma unroll
      for (int mt = 0; mt < 4; ++mt)
#pragma unroll
        for (int nt = 0; nt < 4; ++nt) {
          acc[mt][nt] = __builtin_amdgcn_mfma_f32_16x16x32_bf16(ah[mt], bh[nt], acc[mt][nt], 0, 0, 0);
          acc[mt][nt] = __builtin_amdgcn_mfma_f32_16x16x32_bf16(ah[mt], bl[nt], acc[mt][nt], 0, 0, 0);
          acc[mt][nt] = __builtin_amdgcn_mfma_f32_16x16x32_bf16(al[mt], bh[nt], acc[mt][nt], 0, 0, 0);
        }
    }
    __syncthreads();
  }

  // ---- epilogue: logits + gumbel + per-row argmax over this wave's 64 cols ----
  const int cl = lane & 15;
  const int q4 = (lane >> 4) * 4;
  const int coff = c_base + (w & 1) * 64;
  const int roff = j_base + (w >> 1) * 64;
  float invc[4]; int colg[4];
#pragma unroll
  for (int nt = 0; nt < 4; ++nt) {
    colg[nt] = coff + nt * 16 + cl;
    invc[nt] = inv_norm[colg[nt]];
  }
#pragma unroll
  for (int mt = 0; mt < 4; ++mt)
#pragma unroll
    for (int r = 0; r < 4; ++r) {
      int gj = roff + mt * 16 + q4 + r;
      int s = src_idx[min(gj, NH - 1)];
      float invs = inv_norm[s];
      uint32_t pbase = (uint32_t)gj * (uint32_t)BN;
      float bv = -INFINITY; uint32_t bc = 0;
#pragma unroll
      for (int nt = 0; nt < 4; ++nt) {
        float sim = acc[mt][nt][r] * invs * invc[nt];
        float gmb = gumbel_at(kt0, kt1, pbase + (uint32_t)colg[nt]);
        float tot = fmaf(sim, 10.0f, gmb);     // logits = sim / 0.1
        if (colg[nt] == s) tot = -INFINITY;    // diagonal mask
        if (tot > bv) { bv = tot; bc = (uint32_t)colg[nt]; }
      }
      unsigned long long key = packvc(bv, bc);
#pragma unroll
      for (int off = 1; off <= 8; off <<= 1) {
        unsigned long long o = __shfl_xor(key, off, 64);
        if (o > key) key = o;
      }
      if (cl == 0 && gj < NH) atomicMax(&best[gj], key);
    }
}

__global__ __launch_bounds__(64) void k_out(const float* __restrict__ z,
                                            const int* __restrict__ src_idx,
                                            const unsigned long long* __restrict__ best,
                                            float* __restrict__ out,
                                            uint32_t ka0, uint32_t ka1) {
  int j = blockIdx.x;
  int lane = threadIdx.x;
  int s = src_idx[j];
  int tgt = (int)(~((uint32_t)(best[j] & 0xFFFFFFFFull)));
  uint32_t bits = rand32_at(ka0, ka1, (uint32_t)j);
  float alpha = unif01_from_bits(bits) * 0.5f;   // uniform * MIX_ALPHA
  float om = 1.0f - alpha;
  float4 a = *(const float4*)&z[s * DK + lane * 4];
  float4 b = *(const float4*)&z[tgt * DK + lane * 4];
  float4 o;
  o.x = alpha * a.x + om * b.x;
  o.y = alpha * a.y + om * b.y;
  o.z = alpha * a.z + om * b.z;
  o.w = alpha * a.w + om * b.w;
  *(float4*)&out[j * DK + lane * 4] = o;
}

// ---------------------------------------------------------------------------
extern "C" void kernel_launch(void* const* d_in, const int* in_sizes, int n_in,
                              void* d_out, int out_size, void* d_ws, size_t ws_size,
                              hipStream_t stream) {
  const float* z = (const float*)d_in[0];
  float* out = (float*)d_out;
  char* ws = (char*)d_ws;
  float*              inv_norm = (float*)(ws);                     // 65536 B
  int*                src_idx  = (int*)(ws + 65536);               // 13104 B
  unsigned long long* best     = (unsigned long long*)(ws + 78656); // 26208 B

  // host-side threefry key derivation (partitionable scheme, verified round 1)
  uint32_t r0 = 0u, r1 = 42u;
  uint32_t ks0, ks1, kt0, kt1, ka0, ka1, k20, k21;
  tf2x32(r0, r1, 0u, 0u, ks0, ks1);   // k_src   = split(root,3)[0]
  tf2x32(r0, r1, 0u, 1u, kt0, kt1);   // k_tgt   = split(root,3)[1]
  tf2x32(r0, r1, 0u, 2u, ka0, ka1);   // k_alpha = split(root,3)[2]
  tf2x32(ks0, ks1, 0u, 1u, k20, k21); // split(k_src,2)[1] (randint lower bits)

  k_norm <<<dim3(BN / 4), dim3(256), 0, stream>>>(z, inv_norm);
  k_setup<<<dim3((NH + 255) / 256), dim3(256), 0, stream>>>(src_idx, best, k20, k21);
  k_main <<<dim3(NCB * NJB), dim3(256), 0, stream>>>(z, inv_norm, src_idx, best, kt0, kt1);
  k_out  <<<dim3(NH), dim3(64), 0, stream>>>(z, src_idx, best, out, ka0, ka1);
}

// Round 3
// 283.975 us; speedup vs baseline: 2.1079x; 1.0733x over previous
//
#include <hip/hip_runtime.h>
#include <stdint.h>
#include <math.h>

// ---------------------------------------------------------------------------
// HardNegativeMiner round 3: pre-converted bf16 hi/lo z (split-bf16 3-pass
// MFMA), global_load_lds 16B async staging with swizzle-inverted source
// addressing, KC=32 -> 32 KB LDS -> 4 blocks/CU.
// Workspace: ~17 MB (z_hi + z_lo bf16 copies).
// PRNG chain (partitionable threefry) verified bit-exact in rounds 1-2.
// ---------------------------------------------------------------------------
#define BN 16384   // batch
#define DK 256     // dim
#define NH 3276    // int(16384*0.2)
#define NJB 26     // j-strips of 128
#define NCB 128    // c-blocks of 128

typedef __attribute__((ext_vector_type(8))) short short8;
typedef __attribute__((ext_vector_type(4))) short short4v;
typedef __attribute__((ext_vector_type(4))) float f32x4;

__host__ __device__ __forceinline__ void tf2x32(uint32_t k0, uint32_t k1,
                                                uint32_t c0, uint32_t c1,
                                                uint32_t& o0, uint32_t& o1) {
  uint32_t ks2 = 0x1BD11BDAu ^ k0 ^ k1;
  uint32_t x0 = c0 + k0, x1 = c1 + k1;
#define RR(d) { x0 += x1; x1 = (x1 << d) | (x1 >> (32 - d)); x1 ^= x0; }
  RR(13) RR(15) RR(26) RR(6)   x0 += k1;  x1 += ks2 + 1u;
  RR(17) RR(29) RR(16) RR(24)  x0 += ks2; x1 += k0  + 2u;
  RR(13) RR(15) RR(26) RR(6)   x0 += k0;  x1 += k1  + 3u;
  RR(17) RR(29) RR(16) RR(24)  x0 += k1;  x1 += ks2 + 4u;
  RR(13) RR(15) RR(26) RR(6)   x0 += ks2; x1 += k0  + 5u;
#undef RR
  o0 = x0; o1 = x1;
}

__device__ __forceinline__ uint32_t rand32_at(uint32_t k0, uint32_t k1, uint32_t p) {
  uint32_t x0, x1; tf2x32(k0, k1, 0u, p, x0, x1);
  return x0 ^ x1;
}

__device__ __forceinline__ float unif01_from_bits(uint32_t bits) {
  return __uint_as_float((bits >> 9) | 0x3f800000u) - 1.0f;
}

// gumbel at flat counter p: -log(-log(max(u, tiny))), fast v_log_f32 path
__device__ __forceinline__ float gumbel_at(uint32_t k0, uint32_t k1, uint32_t p) {
  uint32_t bits = rand32_at(k0, k1, p);
  float f = unif01_from_bits(bits);
  float u = fmaxf(f, 1.17549435e-38f);             // minval = finfo(f32).tiny
  float t = __log2f(u) * (-0.69314718055994531f);  // -ln(u) > 0
  return __log2f(t) * (-0.69314718055994531f);     // -ln(t)
}

// monotonic float->u32; pack (value, ~col): max => larger val, tie => smaller col
__device__ __forceinline__ unsigned long long packvc(float v, uint32_t c) {
  uint32_t u = __float_as_uint(v);
  u ^= ((int32_t)u < 0) ? 0xFFFFFFFFu : 0x80000000u;
  return ((unsigned long long)u << 32) | (unsigned long long)(~c);
}

// 16-byte global -> LDS async DMA. LDS dest is wave-uniform base + lane*16.
__device__ __forceinline__ void glds16(const unsigned short* g, short* l) {
  __builtin_amdgcn_global_load_lds(
      (const __attribute__((address_space(1))) void*)g,
      (__attribute__((address_space(3))) void*)l, 16, 0, 0);
}

// ---------------------------------------------------------------------------
// Fused: row inv-norms + fp32 -> (bf16 hi, bf16 lo) split copy + src_idx/best
// setup. hi = trunc-to-bf16(f); lo = trunc-to-bf16(f - hi); identical numerics
// to round 2's in-kernel split.
__global__ __launch_bounds__(256) void k_prep(const float* __restrict__ z,
                                              float* __restrict__ inv_norm,
                                              unsigned short* __restrict__ zh,
                                              unsigned short* __restrict__ zl,
                                              int* __restrict__ src_idx,
                                              unsigned long long* __restrict__ best,
                                              uint32_t k20, uint32_t k21) {
  int b = blockIdx.x, t = threadIdx.x;
  if (b < BN / 4) {
    int row = b * 4 + (t >> 6), lane = t & 63;
    float4 v = *(const float4*)&z[row * DK + lane * 4];
    float ss = v.x * v.x + v.y * v.y + v.z * v.z + v.w * v.w;
#pragma unroll
    for (int off = 32; off; off >>= 1) ss += __shfl_xor(ss, off, 64);
    if (lane == 0) inv_norm[row] = 1.0f / fmaxf(sqrtf(ss), 1e-12f);
    float f[4] = {v.x, v.y, v.z, v.w};
    short4v h, l;
#pragma unroll
    for (int i = 0; i < 4; ++i) {
      uint32_t u = __float_as_uint(f[i]);
      h[i] = (short)(u >> 16);
      float r = f[i] - __uint_as_float(u & 0xFFFF0000u);
      l[i] = (short)(__float_as_uint(r) >> 16);
    }
    *(short4v*)&zh[row * DK + lane * 4] = h;
    *(short4v*)&zl[row * DK + lane * 4] = l;
  } else {
    int i = (b - BN / 4) * 256 + t;
    if (i < NH) {
      uint32_t bits = rand32_at(k20, k21, (uint32_t)i);
      src_idx[i] = (int)(bits & (uint32_t)(BN - 1));  // randint span 2^14
      best[i] = 0ull;                                 // identity for packvc keys
    }
  }
}

// ---------------------------------------------------------------------------
// 128x128 block tile, 4 waves of 64x64, K=256 in 8 chunks of 32.
// LDS tiles: rows of 32 shorts (64 B). Data-unit u (8 shorts) stored at
// su = u ^ ((row>>1)&3) -> fragment ds_read_b128 spreads 2-way over bank
// quads (free). global_load_lds source addresses carry the inverse swizzle.
__global__ __launch_bounds__(256, 4) void k_main(const unsigned short* __restrict__ zh,
                                                 const unsigned short* __restrict__ zl,
                                                 const float* __restrict__ inv_norm,
                                                 const int* __restrict__ src_idx,
                                                 unsigned long long* __restrict__ best,
                                                 uint32_t kt0, uint32_t kt1) {
  __shared__ __align__(16) short As_hi[128 * 32];
  __shared__ __align__(16) short As_lo[128 * 32];
  __shared__ __align__(16) short Bs_hi[128 * 32];
  __shared__ __align__(16) short Bs_lo[128 * 32];

  // XCD-aware swizzle: XCD x owns c-blocks [16x, 16x+16) -> 2 MB B-set per L2
  const int flat = blockIdx.x;                 // 3328 = 8 * (16 * 26)
  const int xcd = flat & 7, slot = flat >> 3;  // slot in [0, 416)
  const int c_base = (xcd * 16 + (slot & 15)) * 128;
  const int j_base = (slot >> 4) * 128;

  const int t = threadIdx.x;
  const int lane = t & 63, w = t >> 6;

  // staging: wave w DMAs chunks {2w, 2w+1} (16 rows x 1 KB each) of all 4 tiles
  const int r0 = w * 32 + (lane >> 2);          // row for chunk 2w
  const int r1 = r0 + 16;                       // row for chunk 2w+1
  const int u0 = (lane & 3) ^ ((r0 >> 1) & 3);  // data-unit that lands at this lane
  const int u1 = (lane & 3) ^ ((r1 >> 1) & 3);
  const int ga0 = src_idx[min(j_base + r0, NH - 1)];
  const int ga1 = src_idx[min(j_base + r1, NH - 1)];
  const size_t offA0 = (size_t)ga0 * DK + u0 * 8;
  const size_t offA1 = (size_t)ga1 * DK + u1 * 8;
  const size_t offB0 = (size_t)(c_base + r0) * DK + u0 * 8;
  const size_t offB1 = (size_t)(c_base + r1) * DK + u1 * 8;
  short* dA = &As_hi[w * 1024];   // same offsets valid for all 4 tile buffers
  short* dAl = &As_lo[w * 1024];
  short* dB = &Bs_hi[w * 1024];
  short* dBl = &Bs_lo[w * 1024];

  // fragment roles (all LDS addresses kc-invariant)
  const int cl = lane & 15, q = lane >> 4;
  const int mb = (w >> 1) * 64 + cl;
  const int nb = (w & 1) * 64 + cl;

  f32x4 acc[4][4];
#pragma unroll
  for (int mt = 0; mt < 4; ++mt)
#pragma unroll
    for (int nt = 0; nt < 4; ++nt) acc[mt][nt] = (f32x4){0.f, 0.f, 0.f, 0.f};

#pragma unroll
  for (int kc = 0; kc < 8; ++kc) {
    const int ko = kc * 32;
    glds16(zh + offA0 + ko, dA);
    glds16(zh + offA1 + ko, dA + 512);
    glds16(zl + offA0 + ko, dAl);
    glds16(zl + offA1 + ko, dAl + 512);
    glds16(zh + offB0 + ko, dB);
    glds16(zh + offB1 + ko, dB + 512);
    glds16(zl + offB0 + ko, dBl);
    glds16(zl + offB1 + ko, dBl + 512);
    __syncthreads();

    short8 bh[4], bl[4];
#pragma unroll
    for (int nt = 0; nt < 4; ++nt) {
      int row = nb + nt * 16;
      int off = row * 32 + (q ^ ((row >> 1) & 3)) * 8;
      bh[nt] = *(const short8*)&Bs_hi[off];
      bl[nt] = *(const short8*)&Bs_lo[off];
    }
#pragma unroll
    for (int mt = 0; mt < 4; ++mt) {
      int row = mb + mt * 16;
      int off = row * 32 + (q ^ ((row >> 1) & 3)) * 8;
      short8 ah = *(const short8*)&As_hi[off];
      short8 al = *(const short8*)&As_lo[off];
#pragma unroll
      for (int nt = 0; nt < 4; ++nt) {
        acc[mt][nt] = __builtin_amdgcn_mfma_f32_16x16x32_bf16(ah, bh[nt], acc[mt][nt], 0, 0, 0);
        acc[mt][nt] = __builtin_amdgcn_mfma_f32_16x16x32_bf16(ah, bl[nt], acc[mt][nt], 0, 0, 0);
        acc[mt][nt] = __builtin_amdgcn_mfma_f32_16x16x32_bf16(al, bh[nt], acc[mt][nt], 0, 0, 0);
      }
    }
    __syncthreads();
  }

  // ---- epilogue: logits + gumbel + per-row argmax over this wave's 64 cols ----
  const int q4 = (lane >> 4) * 4;
  const int coff = c_base + (w & 1) * 64;
  const int roff = j_base + (w >> 1) * 64;
  float invc[4]; int colg[4];
#pragma unroll
  for (int nt = 0; nt < 4; ++nt) {
    colg[nt] = coff + nt * 16 + cl;
    invc[nt] = inv_norm[colg[nt]];
  }
#pragma unroll
  for (int mt = 0; mt < 4; ++mt)
#pragma unroll
    for (int r = 0; r < 4; ++r) {
      int gj = roff + mt * 16 + q4 + r;
      int s = src_idx[min(gj, NH - 1)];
      float invs = inv_norm[s];
      uint32_t pbase = (uint32_t)gj * (uint32_t)BN;
      float bv = -INFINITY; uint32_t bc = 0;
#pragma unroll
      for (int nt = 0; nt < 4; ++nt) {
        float sim = acc[mt][nt][r] * invs * invc[nt];
        float gmb = gumbel_at(kt0, kt1, pbase + (uint32_t)colg[nt]);
        float tot = fmaf(sim, 10.0f, gmb);     // logits = sim / 0.1
        if (colg[nt] == s) tot = -INFINITY;    // diagonal mask
        if (tot > bv) { bv = tot; bc = (uint32_t)colg[nt]; }
      }
      unsigned long long key = packvc(bv, bc);
#pragma unroll
      for (int off = 1; off <= 8; off <<= 1) {
        unsigned long long o = __shfl_xor(key, off, 64);
        if (o > key) key = o;
      }
      if (cl == 0 && gj < NH) atomicMax(&best[gj], key);
    }
}

__global__ __launch_bounds__(64) void k_out(const float* __restrict__ z,
                                            const int* __restrict__ src_idx,
                                            const unsigned long long* __restrict__ best,
                                            float* __restrict__ out,
                                            uint32_t ka0, uint32_t ka1) {
  int j = blockIdx.x;
  int lane = threadIdx.x;
  int s = src_idx[j];
  int tgt = (int)(~((uint32_t)(best[j] & 0xFFFFFFFFull)));
  uint32_t bits = rand32_at(ka0, ka1, (uint32_t)j);
  float alpha = unif01_from_bits(bits) * 0.5f;   // uniform * MIX_ALPHA
  float om = 1.0f - alpha;
  float4 a = *(const float4*)&z[s * DK + lane * 4];
  float4 b = *(const float4*)&z[tgt * DK + lane * 4];
  float4 o;
  o.x = alpha * a.x + om * b.x;
  o.y = alpha * a.y + om * b.y;
  o.z = alpha * a.z + om * b.z;
  o.w = alpha * a.w + om * b.w;
  *(float4*)&out[j * DK + lane * 4] = o;
}

// ---------------------------------------------------------------------------
extern "C" void kernel_launch(void* const* d_in, const int* in_sizes, int n_in,
                              void* d_out, int out_size, void* d_ws, size_t ws_size,
                              hipStream_t stream) {
  const float* z = (const float*)d_in[0];
  float* out = (float*)d_out;
  char* ws = (char*)d_ws;
  // ws layout (needs ~17 MB):
  float*              inv_norm = (float*)(ws);                      // 64 KB
  int*                src_idx  = (int*)(ws + 65536);                // 16 KB
  unsigned long long* best     = (unsigned long long*)(ws + 81920); // 48 KB pad
  unsigned short*     zh       = (unsigned short*)(ws + 131072);    // 8.39 MB
  unsigned short*     zl       = (unsigned short*)(ws + 131072 + (size_t)BN * DK * 2);

  // host-side threefry key derivation (partitionable scheme, verified round 1)
  uint32_t r0 = 0u, r1 = 42u;
  uint32_t ks0, ks1, kt0, kt1, ka0, ka1, k20, k21;
  tf2x32(r0, r1, 0u, 0u, ks0, ks1);   // k_src   = split(root,3)[0]
  tf2x32(r0, r1, 0u, 1u, kt0, kt1);   // k_tgt   = split(root,3)[1]
  tf2x32(r0, r1, 0u, 2u, ka0, ka1);   // k_alpha = split(root,3)[2]
  tf2x32(ks0, ks1, 0u, 1u, k20, k21); // split(k_src,2)[1] (randint lower bits)

  k_prep<<<dim3(BN / 4 + (NH + 255) / 256), dim3(256), 0, stream>>>(
      z, inv_norm, zh, zl, src_idx, best, k20, k21);
  k_main<<<dim3(NCB * NJB), dim3(256), 0, stream>>>(zh, zl, inv_norm, src_idx, best, kt0, kt1);
  k_out <<<dim3(NH), dim3(64), 0, stream>>>(z, src_idx, best, out, ka0, ka1);
}

// Round 4
// 267.212 us; speedup vs baseline: 2.2401x; 1.0627x over previous
//
#include <hip/hip_runtime.h>
#include <stdint.h>
#include <math.h>

// ---------------------------------------------------------------------------
// HardNegativeMiner round 4: same structure as round 3 (pre-split bf16 hi/lo,
// global_load_lds staging, KC=32), but __launch_bounds__(256,3): round 3's
// (256,4) capped the unified VGPR/AGPR budget at 128; acc used 64 AGPRs and
// the rest spilled (WRITE_SIZE 26->159 MB, VGPR_Count=64). 168-reg budget
// fits 64 AGPR + ~100 arch VGPRs with zero spill.
// PRNG chain (partitionable threefry) verified bit-exact in rounds 1-3.
// ---------------------------------------------------------------------------
#define BN 16384   // batch
#define DK 256     // dim
#define NH 3276    // int(16384*0.2)
#define NJB 26     // j-strips of 128
#define NCB 128    // c-blocks of 128

typedef __attribute__((ext_vector_type(8))) short short8;
typedef __attribute__((ext_vector_type(4))) short short4v;
typedef __attribute__((ext_vector_type(4))) float f32x4;

__host__ __device__ __forceinline__ void tf2x32(uint32_t k0, uint32_t k1,
                                                uint32_t c0, uint32_t c1,
                                                uint32_t& o0, uint32_t& o1) {
  uint32_t ks2 = 0x1BD11BDAu ^ k0 ^ k1;
  uint32_t x0 = c0 + k0, x1 = c1 + k1;
#define RR(d) { x0 += x1; x1 = (x1 << d) | (x1 >> (32 - d)); x1 ^= x0; }
  RR(13) RR(15) RR(26) RR(6)   x0 += k1;  x1 += ks2 + 1u;
  RR(17) RR(29) RR(16) RR(24)  x0 += ks2; x1 += k0  + 2u;
  RR(13) RR(15) RR(26) RR(6)   x0 += k0;  x1 += k1  + 3u;
  RR(17) RR(29) RR(16) RR(24)  x0 += k1;  x1 += ks2 + 4u;
  RR(13) RR(15) RR(26) RR(6)   x0 += ks2; x1 += k0  + 5u;
#undef RR
  o0 = x0; o1 = x1;
}

__device__ __forceinline__ uint32_t rand32_at(uint32_t k0, uint32_t k1, uint32_t p) {
  uint32_t x0, x1; tf2x32(k0, k1, 0u, p, x0, x1);
  return x0 ^ x1;
}

__device__ __forceinline__ float unif01_from_bits(uint32_t bits) {
  return __uint_as_float((bits >> 9) | 0x3f800000u) - 1.0f;
}

// gumbel at flat counter p: -log(-log(max(u, tiny))), fast v_log_f32 path
__device__ __forceinline__ float gumbel_at(uint32_t k0, uint32_t k1, uint32_t p) {
  uint32_t bits = rand32_at(k0, k1, p);
  float f = unif01_from_bits(bits);
  float u = fmaxf(f, 1.17549435e-38f);             // minval = finfo(f32).tiny
  float t = __log2f(u) * (-0.69314718055994531f);  // -ln(u) > 0
  return __log2f(t) * (-0.69314718055994531f);     // -ln(t)
}

// monotonic float->u32; pack (value, ~col): max => larger val, tie => smaller col
__device__ __forceinline__ unsigned long long packvc(float v, uint32_t c) {
  uint32_t u = __float_as_uint(v);
  u ^= ((int32_t)u < 0) ? 0xFFFFFFFFu : 0x80000000u;
  return ((unsigned long long)u << 32) | (unsigned long long)(~c);
}

// 16-byte global -> LDS async DMA. LDS dest is wave-uniform base + lane*16.
__device__ __forceinline__ void glds16(const unsigned short* g, short* l) {
  __builtin_amdgcn_global_load_lds(
      (const __attribute__((address_space(1))) void*)g,
      (__attribute__((address_space(3))) void*)l, 16, 0, 0);
}

// ---------------------------------------------------------------------------
// Fused: row inv-norms + fp32 -> (bf16 hi, bf16 lo) split copy + src_idx/best
// setup. hi = trunc-to-bf16(f); lo = trunc-to-bf16(f - hi).
__global__ __launch_bounds__(256) void k_prep(const float* __restrict__ z,
                                              float* __restrict__ inv_norm,
                                              unsigned short* __restrict__ zh,
                                              unsigned short* __restrict__ zl,
                                              int* __restrict__ src_idx,
                                              unsigned long long* __restrict__ best,
                                              uint32_t k20, uint32_t k21) {
  int b = blockIdx.x, t = threadIdx.x;
  if (b < BN / 4) {
    int row = b * 4 + (t >> 6), lane = t & 63;
    float4 v = *(const float4*)&z[row * DK + lane * 4];
    float ss = v.x * v.x + v.y * v.y + v.z * v.z + v.w * v.w;
#pragma unroll
    for (int off = 32; off; off >>= 1) ss += __shfl_xor(ss, off, 64);
    if (lane == 0) inv_norm[row] = 1.0f / fmaxf(sqrtf(ss), 1e-12f);
    float f[4] = {v.x, v.y, v.z, v.w};
    short4v h, l;
#pragma unroll
    for (int i = 0; i < 4; ++i) {
      uint32_t u = __float_as_uint(f[i]);
      h[i] = (short)(u >> 16);
      float r = f[i] - __uint_as_float(u & 0xFFFF0000u);
      l[i] = (short)(__float_as_uint(r) >> 16);
    }
    *(short4v*)&zh[row * DK + lane * 4] = h;
    *(short4v*)&zl[row * DK + lane * 4] = l;
  } else {
    int i = (b - BN / 4) * 256 + t;
    if (i < NH) {
      uint32_t bits = rand32_at(k20, k21, (uint32_t)i);
      src_idx[i] = (int)(bits & (uint32_t)(BN - 1));  // randint span 2^14
      best[i] = 0ull;                                 // identity for packvc keys
    }
  }
}

// ---------------------------------------------------------------------------
// 128x128 block tile, 4 waves of 64x64, K=256 in 8 chunks of 32.
// LDS tiles: rows of 32 shorts (64 B). Data-unit u (8 shorts) stored at
// su = u ^ ((row>>1)&3) -> fragment ds_read_b128 spreads 2-way over bank
// quads (free). global_load_lds source addresses carry the inverse swizzle.
// launch_bounds(256,3): 168-reg budget -> no spill (see header comment).
__global__ __launch_bounds__(256, 3) void k_main(const unsigned short* __restrict__ zh,
                                                 const unsigned short* __restrict__ zl,
                                                 const float* __restrict__ inv_norm,
                                                 const int* __restrict__ src_idx,
                                                 unsigned long long* __restrict__ best,
                                                 uint32_t kt0, uint32_t kt1) {
  __shared__ __align__(16) short As_hi[128 * 32];
  __shared__ __align__(16) short As_lo[128 * 32];
  __shared__ __align__(16) short Bs_hi[128 * 32];
  __shared__ __align__(16) short Bs_lo[128 * 32];

  // XCD-aware swizzle: XCD x owns c-blocks [16x, 16x+16) -> 2 MB B-set per L2
  const int flat = blockIdx.x;                 // 3328 = 8 * (16 * 26)
  const int xcd = flat & 7, slot = flat >> 3;  // slot in [0, 416)
  const int c_base = (xcd * 16 + (slot & 15)) * 128;
  const int j_base = (slot >> 4) * 128;

  const int t = threadIdx.x;
  const int lane = t & 63, w = t >> 6;

  // staging: wave w DMAs chunks {2w, 2w+1} (16 rows x 1 KB each) of all 4 tiles
  const int r0 = w * 32 + (lane >> 2);          // row for chunk 2w
  const int r1 = r0 + 16;                       // row for chunk 2w+1
  const int u0 = (lane & 3) ^ ((r0 >> 1) & 3);  // data-unit that lands at this lane
  const int u1 = (lane & 3) ^ ((r1 >> 1) & 3);
  const int ga0 = src_idx[min(j_base + r0, NH - 1)];
  const int ga1 = src_idx[min(j_base + r1, NH - 1)];
  const uint32_t offA0 = (uint32_t)(ga0 * DK + u0 * 8);
  const uint32_t offA1 = (uint32_t)(ga1 * DK + u1 * 8);
  const uint32_t offB0 = (uint32_t)((c_base + r0) * DK + u0 * 8);
  const uint32_t offB1 = (uint32_t)((c_base + r1) * DK + u1 * 8);
  short* dA  = &As_hi[w * 1024];  // same offsets valid for all 4 tile buffers
  short* dAl = &As_lo[w * 1024];
  short* dB  = &Bs_hi[w * 1024];
  short* dBl = &Bs_lo[w * 1024];

  // fragment roles (all LDS addresses kc-invariant)
  const int cl = lane & 15, q = lane >> 4;
  const int mb = (w >> 1) * 64 + cl;
  const int nb = (w & 1) * 64 + cl;

  f32x4 acc[4][4];
#pragma unroll
  for (int mt = 0; mt < 4; ++mt)
#pragma unroll
    for (int nt = 0; nt < 4; ++nt) acc[mt][nt] = (f32x4){0.f, 0.f, 0.f, 0.f};

#pragma unroll
  for (int kc = 0; kc < 8; ++kc) {
    const int ko = kc * 32;
    glds16(zh + offA0 + ko, dA);
    glds16(zh + offA1 + ko, dA + 512);
    glds16(zl + offA0 + ko, dAl);
    glds16(zl + offA1 + ko, dAl + 512);
    glds16(zh + offB0 + ko, dB);
    glds16(zh + offB1 + ko, dB + 512);
    glds16(zl + offB0 + ko, dBl);
    glds16(zl + offB1 + ko, dBl + 512);
    __syncthreads();

    short8 bh[4], bl[4];
#pragma unroll
    for (int nt = 0; nt < 4; ++nt) {
      int row = nb + nt * 16;
      int off = row * 32 + (q ^ ((row >> 1) & 3)) * 8;
      bh[nt] = *(const short8*)&Bs_hi[off];
      bl[nt] = *(const short8*)&Bs_lo[off];
    }
#pragma unroll
    for (int mt = 0; mt < 4; ++mt) {
      int row = mb + mt * 16;
      int off = row * 32 + (q ^ ((row >> 1) & 3)) * 8;
      short8 ah = *(const short8*)&As_hi[off];
      short8 al = *(const short8*)&As_lo[off];
#pragma unroll
      for (int nt = 0; nt < 4; ++nt) {
        acc[mt][nt] = __builtin_amdgcn_mfma_f32_16x16x32_bf16(ah, bh[nt], acc[mt][nt], 0, 0, 0);
        acc[mt][nt] = __builtin_amdgcn_mfma_f32_16x16x32_bf16(ah, bl[nt], acc[mt][nt], 0, 0, 0);
        acc[mt][nt] = __builtin_amdgcn_mfma_f32_16x16x32_bf16(al, bh[nt], acc[mt][nt], 0, 0, 0);
      }
    }
    __syncthreads();
  }

  // ---- epilogue: logits + gumbel + per-row argmax over this wave's 64 cols ----
  const int q4 = (lane >> 4) * 4;
  const int coff = c_base + (w & 1) * 64;
  const int roff = j_base + (w >> 1) * 64;
  float invc[4]; int colg[4];
#pragma unroll
  for (int nt = 0; nt < 4; ++nt) {
    colg[nt] = coff + nt * 16 + cl;
    invc[nt] = inv_norm[colg[nt]];
  }
#pragma unroll
  for (int mt = 0; mt < 4; ++mt)
#pragma unroll
    for (int r = 0; r < 4; ++r) {
      int gj = roff + mt * 16 + q4 + r;
      int s = src_idx[min(gj, NH - 1)];
      float invs = inv_norm[s];
      uint32_t pbase = (uint32_t)gj * (uint32_t)BN;
      float bv = -INFINITY; uint32_t bc = 0;
#pragma unroll
      for (int nt = 0; nt < 4; ++nt) {
        float sim = acc[mt][nt][r] * invs * invc[nt];
        float gmb = gumbel_at(kt0, kt1, pbase + (uint32_t)colg[nt]);
        float tot = fmaf(sim, 10.0f, gmb);     // logits = sim / 0.1
        if (colg[nt] == s) tot = -INFINITY;    // diagonal mask
        if (tot > bv) { bv = tot; bc = (uint32_t)colg[nt]; }
      }
      unsigned long long key = packvc(bv, bc);
#pragma unroll
      for (int off = 1; off <= 8; off <<= 1) {
        unsigned long long o = __shfl_xor(key, off, 64);
        if (o > key) key = o;
      }
      if (cl == 0 && gj < NH) atomicMax(&best[gj], key);
    }
}

__global__ __launch_bounds__(64) void k_out(const float* __restrict__ z,
                                            const int* __restrict__ src_idx,
                                            const unsigned long long* __restrict__ best,
                                            float* __restrict__ out,
                                            uint32_t ka0, uint32_t ka1) {
  int j = blockIdx.x;
  int lane = threadIdx.x;
  int s = src_idx[j];
  int tgt = (int)(~((uint32_t)(best[j] & 0xFFFFFFFFull)));
  uint32_t bits = rand32_at(ka0, ka1, (uint32_t)j);
  float alpha = unif01_from_bits(bits) * 0.5f;   // uniform * MIX_ALPHA
  float om = 1.0f - alpha;
  float4 a = *(const float4*)&z[s * DK + lane * 4];
  float4 b = *(const float4*)&z[tgt * DK + lane * 4];
  float4 o;
  o.x = alpha * a.x + om * b.x;
  o.y = alpha * a.y + om * b.y;
  o.z = alpha * a.z + om * b.z;
  o.w = alpha * a.w + om * b.w;
  *(float4*)&out[j * DK + lane * 4] = o;
}

// ---------------------------------------------------------------------------
extern "C" void kernel_launch(void* const* d_in, const int* in_sizes, int n_in,
                              void* d_out, int out_size, void* d_ws, size_t ws_size,
                              hipStream_t stream) {
  const float* z = (const float*)d_in[0];
  float* out = (float*)d_out;
  char* ws = (char*)d_ws;
  // ws layout (needs ~17 MB):
  float*              inv_norm = (float*)(ws);                      // 64 KB
  int*                src_idx  = (int*)(ws + 65536);                // 16 KB
  unsigned long long* best     = (unsigned long long*)(ws + 81920); // 48 KB pad
  unsigned short*     zh       = (unsigned short*)(ws + 131072);    // 8.39 MB
  unsigned short*     zl       = (unsigned short*)(ws + 131072 + (size_t)BN * DK * 2);

  // host-side threefry key derivation (partitionable scheme, verified round 1)
  uint32_t r0 = 0u, r1 = 42u;
  uint32_t ks0, ks1, kt0, kt1, ka0, ka1, k20, k21;
  tf2x32(r0, r1, 0u, 0u, ks0, ks1);   // k_src   = split(root,3)[0]
  tf2x32(r0, r1, 0u, 1u, kt0, kt1);   // k_tgt   = split(root,3)[1]
  tf2x32(r0, r1, 0u, 2u, ka0, ka1);   // k_alpha = split(root,3)[2]
  tf2x32(ks0, ks1, 0u, 1u, k20, k21); // split(k_src,2)[1] (randint lower bits)

  k_prep<<<dim3(BN / 4 + (NH + 255) / 256), dim3(256), 0, stream>>>(
      z, inv_norm, zh, zl, src_idx, best, k20, k21);
  k_main<<<dim3(NCB * NJB), dim3(256), 0, stream>>>(zh, zl, inv_norm, src_idx, best, kt0, kt1);
  k_out <<<dim3(NH), dim3(64), 0, stream>>>(z, src_idx, best, out, ka0, ka1);
}